// Round 1
// baseline (662.979 us; speedup 1.0000x reference)
//
#include <hip/hip_runtime.h>
#include <hip/hip_bf16.h>
#include <math.h>

typedef __bf16 bf16;
typedef __attribute__((ext_vector_type(8))) __bf16 bf16x8;
typedef __attribute__((ext_vector_type(4))) float f32x4;

typedef const uint32_t __attribute__((address_space(1)))* gp1_t;
typedef uint32_t __attribute__((address_space(3)))* lp3_t;

__device__ __forceinline__ void async_load16(const void* g, void* l) {
    // global -> LDS direct, 16B per lane; LDS dest = wave-uniform base + lane*16
    __builtin_amdgcn_global_load_lds((gp1_t)g, (lp3_t)l, 16, 0, 0);
}

__device__ __forceinline__ float softplus_f(float x) {
    // fast-math softplus: x in [-3.5,-2.5] here; __logf on (1,2] is ~1e-7 abs err,
    // negligible vs bf16 rounding of the sampled weight.
    return fmaxf(x, 0.0f) + __logf(1.0f + __expf(-fabsf(x)));
}

#define IN_F  4096
#define OUT_F 4096
#define BATCH 8192

#define BM 256
#define BN 256

// blocks for the two prologue regions
#define NXB ((BATCH * IN_F) / (256 * 8))   // 16384: x fp32->bf16
#define NWB ((OUT_F * IN_F) / (256 * 8))   //  8192: W = mu + softplus(rho)*eps

// ---- Fused prologue: region 0 converts x, region 1 samples W ----
__global__ __launch_bounds__(256) void prologue(
    const float* __restrict__ x,
    const float* __restrict__ mu, const float* __restrict__ rho,
    const float* __restrict__ eps,
    bf16* __restrict__ xb, bf16* __restrict__ W)
{
    const int b = blockIdx.x;
    if (b < NXB) {
        const int i = (b * 256 + threadIdx.x) * 8;
        float4 a = *(const float4*)(x + i);
        float4 c = *(const float4*)(x + i + 4);
        bf16x8 o;
        o[0] = (bf16)a.x; o[1] = (bf16)a.y; o[2] = (bf16)a.z; o[3] = (bf16)a.w;
        o[4] = (bf16)c.x; o[5] = (bf16)c.y; o[6] = (bf16)c.z; o[7] = (bf16)c.w;
        *(bf16x8*)(xb + i) = o;
    } else {
        const int i = ((b - NXB) * 256 + threadIdx.x) * 8;
        bf16x8 w;
#pragma unroll
        for (int h = 0; h < 2; ++h) {
            float4 m = *(const float4*)(mu + i + h * 4);
            float4 r = *(const float4*)(rho + i + h * 4);
            float4 e = *(const float4*)(eps + i + h * 4);
            w[h * 4 + 0] = (bf16)(m.x + softplus_f(r.x) * e.x);
            w[h * 4 + 1] = (bf16)(m.y + softplus_f(r.y) * e.y);
            w[h * 4 + 2] = (bf16)(m.z + softplus_f(r.z) * e.z);
            w[h * 4 + 3] = (bf16)(m.w + softplus_f(r.w) * e.w);
        }
        *(bf16x8*)(W + i) = w;
    }
}

// ---------------------------------------------------------------------------
// 256x256-tile 8-phase GEMM (HK-style schedule in plain HIP):
//   C[M,N] = A[M,K] * W[N,K]^T + bias, bf16 inputs, fp32 out.
// 8 waves (2M x 4N), BK=64, 2 K-tiles per iteration, 8 phases/iter.
// LDS 128 KiB: [buf][mat(A/B)][half][128 rows x 64 k] bf16, XOR-swizzled
//   byte ^= (row&7)<<4 : applied on the READ address and (inversely) on the
//   pre-swizzled GLOBAL source of global_load_lds (linear LDS dest).
// Counted vmcnt(4) only at phases 4 and 8; raw s_barrier (no drain).
// Stage targets are always slots fully consumed >=1 barrier earlier:
//   per K-tile t phases: ph1 reads a-mh0+b-nh0, ph2 reads a-mh1+b-nh1
//   (tile's LDS dead after ph2's lgkmcnt(0)+barrier),
//   ph1 stages (t+1).B0, ph2 (t+1).B1, ph3 (t+2).A0, ph4 (t+2).A1.
// ---------------------------------------------------------------------------
__global__ __launch_bounds__(512, 2) void gemm_bt_bias(
    const bf16* __restrict__ A,    // x bf16 [M,K]
    const bf16* __restrict__ W,    // sampled weight bf16 [N,K]
    const float* __restrict__ bmu, const float* __restrict__ brho,
    const float* __restrict__ beps,
    float* __restrict__ C)         // [M,N] fp32
{
    __shared__ __align__(16) bf16 lds[2][2][2][128 * 64];  // 128 KiB

    const int tid  = threadIdx.x;
    const int lane = tid & 63;
    const int l15  = lane & 15;
    const int quad = lane >> 4;

    const int bn = blockIdx.x & 15;       // N/BN = 16
    const int bm = blockIdx.x >> 4;       // M/BM = 32
    const int row0 = bm * BM;
    const int col0 = bn * BN;

    const int wave = tid >> 6;
    const int wmh = wave >> 2;            // which A half-tile (C row block)
    const int wnq = wave & 3;
    const int wbh = wnq >> 1;             // which B half-tile slot
    const int nb  = (wnq & 1) * 64;       // row base within B slot

    const f32x4 zero = {0.f, 0.f, 0.f, 0.f};
    f32x4 acc[8][4];
#pragma unroll
    for (int i2 = 0; i2 < 8; ++i2)
#pragma unroll
        for (int j2 = 0; j2 < 4; ++j2) acc[i2][j2] = zero;

    const int ldsw = (tid & ~63) * 16;    // wave * 1024 (wave-uniform)

    // Stage half-tile m (0=A0,1=A1,2=B0,3=B1) of K-tile t.
    // buf keeps true parity even for clamped tail tiles (vmcnt counts exact;
    // clamped garbage lands only in dead slots, never read).
    auto STAGE = [&](int m, int t) {
        const int buf = t & 1;
        const int k0  = (t < (IN_F / 64) ? t : (IN_F / 64 - 1)) << 6;
        const bf16* g = (m < 2) ? A : W;
        const int gr  = ((m < 2) ? row0 : col0) + ((m & 1) << 7);
        char* slot = (char*)&lds[buf][m >> 1][m & 1][0];
#pragma unroll
        for (int j = 0; j < 2; ++j) {
            const int p    = j * 8192 + tid * 16;        // linear LDS byte
            const int r    = p >> 7;                      // row (128B rows)
            const int irow = (p & 127) ^ ((r & 7) << 4);  // inverse swizzle
            async_load16(g + (size_t)(gr + r) * IN_F + k0 + (irow >> 1),
                         slot + j * 8192 + ldsw);
        }
    };

    // Swizzled fragment read: 16B at (row, kq*32 + quad*8) of a 128x64 slot.
#define FRAG(SLOT, ROW, KQ)                                                  \
    (*(const bf16x8*)((SLOT) + (ROW) * 128 +                                 \
                      (((KQ) * 64 + quad * 16) ^ (((ROW) & 7) << 4))))

#define MFMA_Q(AF, BF, MB, NB_)                                              \
    {                                                                        \
        _Pragma("unroll")                                                    \
        for (int kq = 0; kq < 2; ++kq)                                       \
            _Pragma("unroll")                                                \
            for (int f = 0; f < 4; ++f)                                      \
                _Pragma("unroll")                                            \
                for (int g2 = 0; g2 < 2; ++g2)                               \
                    acc[(MB) + f][(NB_) + g2] =                              \
                        __builtin_amdgcn_mfma_f32_16x16x32_bf16(             \
                            AF[f][kq], BF[g2][kq],                           \
                            acc[(MB) + f][(NB_) + g2], 0, 0, 0);             \
    }

    // Prologue: tile0 fully + tile1 A halves; wait so tile0 landed
    // (newest 2 half-tiles = 4 loads may stay in flight).
    STAGE(0, 0); STAGE(1, 0); STAGE(2, 0); STAGE(3, 0);
    STAGE(0, 1); STAGE(1, 1);
    asm volatile("s_waitcnt vmcnt(4)" ::: "memory");
    asm volatile("s_barrier" ::: "memory");

    bf16x8 a0[4][2], a1[4][2], b0[2][2], b1[2][2];

    for (int i = 0; i < IN_F / 128; ++i) {    // 32 iterations x 2 K-tiles
#pragma unroll
        for (int h = 0; h < 2; ++h) {
            const int tc = 2 * i + h;         // current tile; buf == h
            const char* SA = (const char*)&lds[h][0][wmh][0];
            const char* SB = (const char*)&lds[h][1][wbh][0];

            // ---- phase 1: read a-mh0 + b-nh0 ; stage (tc+1).B0
#pragma unroll
            for (int f = 0; f < 4; ++f) {
                a0[f][0] = FRAG(SA, f * 16 + l15, 0);
                a0[f][1] = FRAG(SA, f * 16 + l15, 1);
            }
#pragma unroll
            for (int f = 0; f < 2; ++f) {
                b0[f][0] = FRAG(SB, nb + f * 16 + l15, 0);
                b0[f][1] = FRAG(SB, nb + f * 16 + l15, 1);
            }
            STAGE(2, tc + 1);
            asm volatile("s_barrier" ::: "memory");
            asm volatile("s_waitcnt lgkmcnt(0)" ::: "memory");
            __builtin_amdgcn_sched_barrier(0);
            __builtin_amdgcn_s_setprio(1);
            MFMA_Q(a0, b0, 0, 0);
            __builtin_amdgcn_s_setprio(0);
            asm volatile("s_barrier" ::: "memory");

            // ---- phase 2: read a-mh1 + b-nh1 ; stage (tc+1).B1
#pragma unroll
            for (int f = 0; f < 4; ++f) {
                a1[f][0] = FRAG(SA, 64 + f * 16 + l15, 0);
                a1[f][1] = FRAG(SA, 64 + f * 16 + l15, 1);
            }
#pragma unroll
            for (int f = 0; f < 2; ++f) {
                b1[f][0] = FRAG(SB, nb + 32 + f * 16 + l15, 0);
                b1[f][1] = FRAG(SB, nb + 32 + f * 16 + l15, 1);
            }
            STAGE(3, tc + 1);
            asm volatile("s_barrier" ::: "memory");
            asm volatile("s_waitcnt lgkmcnt(0)" ::: "memory");
            __builtin_amdgcn_sched_barrier(0);
            __builtin_amdgcn_s_setprio(1);
            MFMA_Q(a0, b1, 0, 2);
            __builtin_amdgcn_s_setprio(0);
            asm volatile("s_barrier" ::: "memory");

            // ---- phase 3: stage (tc+2).A0 (tile tc's LDS is dead now)
            STAGE(0, tc + 2);
            asm volatile("s_barrier" ::: "memory");
            __builtin_amdgcn_s_setprio(1);
            MFMA_Q(a1, b0, 4, 0);
            __builtin_amdgcn_s_setprio(0);
            asm volatile("s_barrier" ::: "memory");

            // ---- phase 4: stage (tc+2).A1 ; counted vmcnt, never 0
            STAGE(1, tc + 2);
            asm volatile("s_barrier" ::: "memory");
            __builtin_amdgcn_s_setprio(1);
            MFMA_Q(a1, b1, 4, 2);
            __builtin_amdgcn_s_setprio(0);
            asm volatile("s_waitcnt vmcnt(4)" ::: "memory");
            asm volatile("s_barrier" ::: "memory");
        }
    }

    // Epilogue: bias = bmu + softplus(brho)*beps, fused (fp32)
    float bias[4];
#pragma unroll
    for (int f = 0; f < 4; ++f) {
        const int col = col0 + wnq * 64 + f * 16 + l15;
        bias[f] = bmu[col] + softplus_f(brho[col]) * beps[col];
    }

    // C/D layout (16x16x32): col = lane&15, row = (lane>>4)*4 + reg
#pragma unroll
    for (int mf = 0; mf < 8; ++mf) {
#pragma unroll
        for (int r = 0; r < 4; ++r) {
            const size_t row = (size_t)row0 + wmh * 128 + mf * 16 + quad * 4 + r;
#pragma unroll
            for (int f = 0; f < 4; ++f) {
                const int col = col0 + wnq * 64 + f * 16 + l15;
                C[row * OUT_F + col] = acc[mf][f][r] + bias[f];
            }
        }
    }
#undef FRAG
#undef MFMA_Q
}

extern "C" void kernel_launch(void* const* d_in, const int* in_sizes, int n_in,
                              void* d_out, int out_size, void* d_ws, size_t ws_size,
                              hipStream_t stream) {
    const float* x    = (const float*)d_in[0];
    const float* wmu  = (const float*)d_in[1];
    const float* wrho = (const float*)d_in[2];
    const float* bmu  = (const float*)d_in[3];
    const float* brho = (const float*)d_in[4];
    const float* weps = (const float*)d_in[5];
    const float* beps = (const float*)d_in[6];
    float* out = (float*)d_out;

    bf16* xb = (bf16*)d_ws;
    bf16* W  = (bf16*)((char*)d_ws + (size_t)BATCH * IN_F * sizeof(bf16));

    prologue<<<NXB + NWB, 256, 0, stream>>>(x, wmu, wrho, weps, xb, W);

    gemm_bt_bias<<<(BATCH / BM) * (OUT_F / BN), 512, 0, stream>>>(
        xb, W, bmu, brho, beps, out);
}